// Round 1
// baseline (3435.667 us; speedup 1.0000x reference)
//
#include <hip/hip_runtime.h>
#include <hip/hip_bf16.h>
#include <math.h>

#define N_OBJ 4096
#define IN_DIM 1024
#define EMB_D 200
#define HID 1024
#define NCLS 151
#define IN_SZ 1224      // IN_DIM + EMB_D
#define NEMB 152        // NCLS + 1 embedding rows
#define R5 5120         // px(1024) + iou(3072) + f(1024) pre-activation rows
#define K2 2048         // visual(1024) + hidden(1024) fused K
#define MAXLVL 48

// ---------------------------------------------------------------------------
// Kernel 1: compute tree depth per step, bucket steps by level (single block).
// parent_pos[t] < t always, so iterative relaxation converges in <= depth passes.
// ---------------------------------------------------------------------------
__global__ __launch_bounds__(1024)
void build_levels(const int* __restrict__ parent_pos,
                  int* __restrict__ level_nodes,
                  int* __restrict__ level_start)
{
    __shared__ int dep[N_OBJ];
    __shared__ int par[N_OBJ];
    __shared__ int cnt[MAXLVL];
    __shared__ int offs[MAXLVL];
    __shared__ int base[MAXLVL + 1];
    __shared__ int done;
    const int tid = threadIdx.x;

    for (int t = tid; t < N_OBJ; t += 1024) {
        int p = parent_pos[t];
        par[t] = p;
        dep[t] = (p < 0) ? 0 : -1;
    }
    for (int l = tid; l < MAXLVL; l += 1024) { cnt[l] = 0; offs[l] = 0; }
    __syncthreads();

    for (int it = 0; it < 64; ++it) {
        if (tid == 0) done = 1;
        __syncthreads();
        for (int t = tid; t < N_OBJ; t += 1024) {
            if (dep[t] < 0) {
                int dp = dep[par[t]];
                if (dp >= 0) dep[t] = dp + 1;
                else done = 0;
            }
        }
        __syncthreads();
        int d = done;
        __syncthreads();
        if (d) break;
    }

    for (int t = tid; t < N_OBJ; t += 1024) {
        int d = dep[t];
        if (d < 0 || d >= MAXLVL) d = MAXLVL - 1;  // safety clamp (never hit for this tree)
        dep[t] = d;
        atomicAdd(&cnt[d], 1);
    }
    __syncthreads();
    if (tid == 0) {
        base[0] = 0;
        for (int l = 0; l < MAXLVL; ++l) base[l + 1] = base[l] + cnt[l];
    }
    __syncthreads();
    for (int t = tid; t < N_OBJ; t += 1024) {
        int d = dep[t];
        int pos = base[d] + atomicAdd(&offs[d], 1);
        level_nodes[pos] = t;
    }
    for (int l = tid; l <= MAXLVL; l += 1024) level_start[l] = base[l];
}

// ---------------------------------------------------------------------------
// Kernel 2: Xemb[e][r] = W_row_r[:, 1024:1224] @ embed_W[e]   (152 x 5120)
// ---------------------------------------------------------------------------
__global__ __launch_bounds__(256)
void xemb_kernel(const float* __restrict__ embed_W,
                 const float* __restrict__ W_px,
                 const float* __restrict__ W_ioux,
                 const float* __restrict__ W_fx,
                 float* __restrict__ Xemb)
{
    __shared__ float e_s[EMB_D];
    const int e = blockIdx.x;
    const int r = blockIdx.y * 256 + threadIdx.x;
    for (int k = threadIdx.x; k < EMB_D; k += 256) e_s[k] = embed_W[(size_t)e * EMB_D + k];
    __syncthreads();

    const float* wrow;
    if (r < HID)            wrow = W_px   + (size_t)r * IN_SZ;
    else if (r < 4 * HID)   wrow = W_ioux + (size_t)(r - HID) * IN_SZ;
    else                    wrow = W_fx   + (size_t)(r - 4 * HID) * IN_SZ;

    float s = 0.f;
    for (int k = 0; k < EMB_D; ++k) s += wrow[IN_DIM + k] * e_s[k];
    Xemb[(size_t)e * R5 + r] = s;
}

// ---------------------------------------------------------------------------
// Kernel 3 (per level): fused GEMM
//   Hbuf[t][r] = Wx_r[0:1024] . features[proc_order[t]]  +  Wh_r . h_all[parent(t)]
//   r in [0,1024):   Wx = W_px row r,           Wh = 0
//   r in [1024,4096): Wx = W_ioux row r-1024,   Wh = W_iouh row r-1024
//   r in [4096,5120): Wx = W_fx row r-4096,     Wh = W_fh row r-4096
// Tile 64(nodes) x 64(rows), BK=32, K=2048, 256 threads, 4x4 micro-tile.
// ---------------------------------------------------------------------------
__global__ __launch_bounds__(256)
void level_gemm(int lvl,
                const int* __restrict__ level_start,
                const int* __restrict__ level_nodes,
                const int* __restrict__ proc_order,
                const int* __restrict__ parent_pos,
                const float* __restrict__ features,
                const float* __restrict__ h_all,
                const float* __restrict__ W_px,
                const float* __restrict__ W_ioux,
                const float* __restrict__ W_fx,
                const float* __restrict__ W_iouh,
                const float* __restrict__ W_fh,
                float* __restrict__ Hbuf)
{
    const int s0 = level_start[lvl];
    const int n  = level_start[lvl + 1] - s0;
    const int bm = blockIdx.y;
    if (bm * 64 >= n) return;            // uniform early exit, before any barrier
    const int bn = blockIdx.x;
    const int r0 = bn * 64;
    const int tid = threadIdx.x;

    __shared__ __align__(16) float As[32][68];
    __shared__ __align__(16) float Bs[32][68];
    __shared__ int s_node[64], s_feat[64], s_par[64];

    if (tid < 64) {
        int m = bm * 64 + tid;
        if (m < n) {
            int t = level_nodes[s0 + m];
            s_node[tid] = t;
            s_feat[tid] = proc_order[t];
            s_par[tid]  = parent_pos[t];
        } else {
            s_node[tid] = -1; s_feat[tid] = -1; s_par[tid] = -1;
        }
    }
    __syncthreads();

    const int tx = tid & 15, ty = tid >> 4;
    const int am = tid >> 2, ka = (tid & 3) << 3;   // A: 64 m x 8 k per thread
    const int br = tid >> 2, kb = (tid & 3) << 3;   // B: 64 n x 8 k per thread

    float acc[4][4] = {{0.f}};

    for (int kt = 0; kt < K2; kt += 32) {
        // ---- stage A tile (nodes x k): visual features then parent hidden ----
        {
            float4 a0 = make_float4(0.f, 0.f, 0.f, 0.f), a1 = a0;
            int fr = s_feat[am];
            int k = kt + ka;
            if (fr >= 0) {
                if (k < IN_DIM) {
                    const float* s = features + (size_t)fr * IN_DIM + k;
                    a0 = *(const float4*)s; a1 = *(const float4*)(s + 4);
                } else {
                    int p = s_par[am];
                    if (p >= 0) {
                        const float* s = h_all + (size_t)p * HID + (k - IN_DIM);
                        a0 = *(const float4*)s; a1 = *(const float4*)(s + 4);
                    }
                }
            }
            As[ka + 0][am] = a0.x; As[ka + 1][am] = a0.y; As[ka + 2][am] = a0.z; As[ka + 3][am] = a0.w;
            As[ka + 4][am] = a1.x; As[ka + 5][am] = a1.y; As[ka + 6][am] = a1.z; As[ka + 7][am] = a1.w;
        }
        // ---- stage B tile (rows x k): select weight matrix by row/k region ----
        {
            float4 b0 = make_float4(0.f, 0.f, 0.f, 0.f), b1 = b0;
            int r = r0 + br;
            int k = kt + kb;
            if (k < IN_DIM) {
                const float* s;
                if (r < HID)          s = W_px   + (size_t)r * IN_SZ + k;
                else if (r < 4 * HID) s = W_ioux + (size_t)(r - HID) * IN_SZ + k;
                else                  s = W_fx   + (size_t)(r - 4 * HID) * IN_SZ + k;
                b0 = *(const float4*)s; b1 = *(const float4*)(s + 4);
            } else if (r >= HID) {
                const float* s;
                if (r < 4 * HID) s = W_iouh + (size_t)(r - HID) * HID + (k - IN_DIM);
                else             s = W_fh   + (size_t)(r - 4 * HID) * HID + (k - IN_DIM);
                b0 = *(const float4*)s; b1 = *(const float4*)(s + 4);
            }
            Bs[kb + 0][br] = b0.x; Bs[kb + 1][br] = b0.y; Bs[kb + 2][br] = b0.z; Bs[kb + 3][br] = b0.w;
            Bs[kb + 4][br] = b1.x; Bs[kb + 5][br] = b1.y; Bs[kb + 6][br] = b1.z; Bs[kb + 7][br] = b1.w;
        }
        __syncthreads();

        #pragma unroll
        for (int k = 0; k < 32; ++k) {
            float4 a = *(const float4*)&As[k][ty << 2];
            float4 b = *(const float4*)&Bs[k][tx << 2];
            acc[0][0] += a.x * b.x; acc[0][1] += a.x * b.y; acc[0][2] += a.x * b.z; acc[0][3] += a.x * b.w;
            acc[1][0] += a.y * b.x; acc[1][1] += a.y * b.y; acc[1][2] += a.y * b.z; acc[1][3] += a.y * b.w;
            acc[2][0] += a.z * b.x; acc[2][1] += a.z * b.y; acc[2][2] += a.z * b.z; acc[2][3] += a.z * b.w;
            acc[3][0] += a.w * b.x; acc[3][1] += a.w * b.y; acc[3][2] += a.w * b.z; acc[3][3] += a.w * b.w;
        }
        __syncthreads();
    }

    #pragma unroll
    for (int i = 0; i < 4; ++i) {
        int ml = (ty << 2) + i;
        if (bm * 64 + ml < n) {
            int t = s_node[ml];
            float4 v = make_float4(acc[i][0], acc[i][1], acc[i][2], acc[i][3]);
            *(float4*)(Hbuf + (size_t)t * R5 + r0 + (tx << 2)) = v;
        }
    }
}

// ---------------------------------------------------------------------------
// Kernel 4 (per level): gates + cell update + output distribution + argmax.
// One block per node in the level.
// ---------------------------------------------------------------------------
__global__ __launch_bounds__(256)
void level_gates(int lvl,
                 const int* __restrict__ level_start,
                 const int* __restrict__ level_nodes,
                 const int* __restrict__ proc_order,
                 const int* __restrict__ parent_pos,
                 const float* __restrict__ Hbuf,
                 const float* __restrict__ Xemb,
                 const float* __restrict__ b_px,
                 const float* __restrict__ b_ioux,
                 const float* __restrict__ b_iouh,
                 const float* __restrict__ b_fx,
                 const float* __restrict__ b_fh,
                 const float* __restrict__ W_out,
                 const float* __restrict__ b_out,
                 float* __restrict__ h_all,
                 float* __restrict__ c_all,
                 int* __restrict__ eidx_all,
                 float* __restrict__ out)
{
    const int s0 = level_start[lvl];
    const int n  = level_start[lvl + 1] - s0;
    const int slot = blockIdx.x;
    if (slot >= n) return;
    const int t = level_nodes[s0 + slot];
    const int pid = parent_pos[t];
    const int eidx = (pid < 0) ? 0 : eidx_all[pid];
    const int tid = threadIdx.x;

    __shared__ __align__(16) float hs[HID];
    __shared__ float bv_s[4];
    __shared__ int   bi_s[4];

    const float* Hr = Hbuf + (size_t)t * R5;
    const float* Er = Xemb + (size_t)eidx * R5;

    for (int j = tid; j < HID; j += 256) {
        float px = Hr[j]           + Er[j]           + b_px[j];
        float ip = Hr[HID + j]     + Er[HID + j]     + b_ioux[j]           + b_iouh[j];
        float op = Hr[2 * HID + j] + Er[2 * HID + j] + b_ioux[HID + j]     + b_iouh[HID + j];
        float up = Hr[3 * HID + j] + Er[3 * HID + j] + b_ioux[2 * HID + j] + b_iouh[2 * HID + j];
        float fp = Hr[4 * HID + j] + Er[4 * HID + j] + b_fx[j]             + b_fh[j];
        float ig = 1.f / (1.f + expf(-ip));
        float og = 1.f / (1.f + expf(-op));
        float ug = tanhf(up);
        float fg = 1.f / (1.f + expf(-fp));
        float pc = (pid < 0) ? 0.f : c_all[(size_t)pid * HID + j];
        float c  = ig * ug + fg * pc;
        float h  = og * tanhf(c) * (1.f / (1.f + expf(-px)));
        c_all[(size_t)t * HID + j] = c;
        h_all[(size_t)t * HID + j] = h;
        hs[j] = h;
    }
    __syncthreads();

    const int node = proc_order[t];
    float* dists = out + (size_t)node * NCLS;
    const int wave = tid >> 6, lane = tid & 63;

    float bv = -3.4e38f; int bi = NCLS;

    for (int r = wave; r < NCLS; r += 4) {
        const float* wr = W_out + (size_t)r * HID;
        float s = 0.f;
        #pragma unroll
        for (int q = 0; q < 4; ++q) {
            float4 w4 = *(const float4*)(wr + (lane << 2) + q * 256);
            float4 h4 = *(const float4*)(hs + (lane << 2) + q * 256);
            s += w4.x * h4.x + w4.y * h4.y + w4.z * h4.z + w4.w * h4.w;
        }
        #pragma unroll
        for (int off = 32; off > 0; off >>= 1) s += __shfl_down(s, off, 64);
        if (lane == 0) {
            s += b_out[r];
            dists[r] = s;
            if (r >= 1 && (s > bv || (s == bv && r < bi))) { bv = s; bi = r; }
        }
    }
    if (lane == 0) { bv_s[wave] = bv; bi_s[wave] = bi; }
    __syncthreads();
    if (tid == 0) {
        float v = bv_s[0]; int b = bi_s[0];
        for (int w = 1; w < 4; ++w) {
            if (bv_s[w] > v || (bv_s[w] == v && bi_s[w] < b)) { v = bv_s[w]; b = bi_s[w]; }
        }
        eidx_all[t] = b + 1;                       // child embedding row = label + 1
        out[(size_t)N_OBJ * NCLS + node] = (float)b;  // commitment as float
    }
}

// ---------------------------------------------------------------------------
extern "C" void kernel_launch(void* const* d_in, const int* in_sizes, int n_in,
                              void* d_out, int out_size, void* d_ws, size_t ws_size,
                              hipStream_t stream)
{
    const float* features = (const float*)d_in[0];
    const float* embed_W  = (const float*)d_in[1];
    const float* W_px     = (const float*)d_in[2];
    const float* b_px     = (const float*)d_in[3];
    const float* W_ioux   = (const float*)d_in[4];
    const float* b_ioux   = (const float*)d_in[5];
    const float* W_iouh   = (const float*)d_in[6];
    const float* b_iouh   = (const float*)d_in[7];
    const float* W_fx     = (const float*)d_in[8];
    const float* b_fx     = (const float*)d_in[9];
    const float* W_fh     = (const float*)d_in[10];
    const float* b_fh     = (const float*)d_in[11];
    const float* W_out    = (const float*)d_in[12];
    const float* b_out    = (const float*)d_in[13];
    const int* proc_order = (const int*)d_in[14];
    const int* parent_pos = (const int*)d_in[15];
    float* out = (float*)d_out;

    // workspace layout (~121 MB)
    float* Hbuf  = (float*)d_ws;                      // [N_OBJ][R5]   pre-activations
    float* h_all = Hbuf + (size_t)N_OBJ * R5;         // [N_OBJ][HID]
    float* c_all = h_all + (size_t)N_OBJ * HID;       // [N_OBJ][HID]
    float* Xemb  = c_all + (size_t)N_OBJ * HID;       // [NEMB][R5]
    int* eidx_all    = (int*)(Xemb + (size_t)NEMB * R5);  // [N_OBJ]
    int* level_nodes = eidx_all + N_OBJ;                  // [N_OBJ]
    int* level_start = level_nodes + N_OBJ;               // [MAXLVL+1]

    build_levels<<<1, 1024, 0, stream>>>(parent_pos, level_nodes, level_start);
    xemb_kernel<<<dim3(NEMB, R5 / 256), 256, 0, stream>>>(embed_W, W_px, W_ioux, W_fx, Xemb);

    for (int l = 0; l < MAXLVL; ++l) {
        level_gemm<<<dim3(R5 / 64, N_OBJ / 64), 256, 0, stream>>>(
            l, level_start, level_nodes, proc_order, parent_pos,
            features, h_all, W_px, W_ioux, W_fx, W_iouh, W_fh, Hbuf);
        level_gates<<<N_OBJ, 256, 0, stream>>>(
            l, level_start, level_nodes, proc_order, parent_pos,
            Hbuf, Xemb, b_px, b_ioux, b_iouh, b_fx, b_fh, W_out, b_out,
            h_all, c_all, eidx_all, out);
    }
}

// Round 2
// 3374.861 us; speedup vs baseline: 1.0180x; 1.0180x over previous
//
#include <hip/hip_runtime.h>
#include <hip/hip_bf16.h>
#include <math.h>

#define N_OBJ 4096
#define IN_DIM 1024
#define EMB_D 200
#define HID 1024
#define NCLS 151
#define IN_SZ 1224      // IN_DIM + EMB_D
#define NEMB 152        // NCLS + 1 embedding rows
#define R5 5120         // px(1024) + iou(3072) + f(1024) pre-activation rows
#define RH 4096         // h-dependent rows (iou 3072 + f 1024)
#define MAXLVL 40       // max depth of random recursive tree (E[max] ~ e ln N ~ 23)

__device__ __forceinline__ float sigf(float x) { return 1.f / (1.f + expf(-x)); }

// ---------------------------------------------------------------------------
// Kernel 1: depth per step, bucket steps by level (single block).
// ---------------------------------------------------------------------------
__global__ __launch_bounds__(1024)
void build_levels(const int* __restrict__ parent_pos,
                  int* __restrict__ level_nodes,
                  int* __restrict__ level_start)
{
    __shared__ int dep[N_OBJ];
    __shared__ int par[N_OBJ];
    __shared__ int cnt[MAXLVL];
    __shared__ int offs[MAXLVL];
    __shared__ int base[MAXLVL + 1];
    __shared__ int done;
    const int tid = threadIdx.x;

    for (int t = tid; t < N_OBJ; t += 1024) {
        int p = parent_pos[t];
        par[t] = p;
        dep[t] = (p < 0) ? 0 : -1;
    }
    for (int l = tid; l < MAXLVL; l += 1024) { cnt[l] = 0; offs[l] = 0; }
    __syncthreads();

    for (int it = 0; it < 64; ++it) {
        if (tid == 0) done = 1;
        __syncthreads();
        for (int t = tid; t < N_OBJ; t += 1024) {
            if (dep[t] < 0) {
                int dp = dep[par[t]];
                if (dp >= 0) dep[t] = dp + 1;
                else done = 0;
            }
        }
        __syncthreads();
        int d = done;
        __syncthreads();
        if (d) break;
    }

    for (int t = tid; t < N_OBJ; t += 1024) {
        int d = dep[t];
        if (d < 0 || d >= MAXLVL) d = MAXLVL - 1;  // safety clamp
        dep[t] = d;
        atomicAdd(&cnt[d], 1);
    }
    __syncthreads();
    if (tid == 0) {
        base[0] = 0;
        for (int l = 0; l < MAXLVL; ++l) base[l + 1] = base[l] + cnt[l];
    }
    __syncthreads();
    for (int t = tid; t < N_OBJ; t += 1024) {
        int d = dep[t];
        int pos = base[d] + atomicAdd(&offs[d], 1);
        level_nodes[pos] = t;
    }
    for (int l = tid; l <= MAXLVL; l += 1024) level_start[l] = base[l];
}

// ---------------------------------------------------------------------------
// Kernel 2: Xemb[e][r] = W_row_r[:, 1024:1224] @ embed_W[e]   (152 x 5120)
// ---------------------------------------------------------------------------
__global__ __launch_bounds__(256)
void xemb_kernel(const float* __restrict__ embed_W,
                 const float* __restrict__ W_px,
                 const float* __restrict__ W_ioux,
                 const float* __restrict__ W_fx,
                 float* __restrict__ Xemb)
{
    __shared__ float e_s[EMB_D];
    const int e = blockIdx.x;
    const int r = blockIdx.y * 256 + threadIdx.x;
    for (int k = threadIdx.x; k < EMB_D; k += 256) e_s[k] = embed_W[(size_t)e * EMB_D + k];
    __syncthreads();

    const float* wrow;
    if (r < HID)            wrow = W_px   + (size_t)r * IN_SZ;
    else if (r < 4 * HID)   wrow = W_ioux + (size_t)(r - HID) * IN_SZ;
    else                    wrow = W_fx   + (size_t)(r - 4 * HID) * IN_SZ;

    float s = 0.f;
    for (int k = 0; k < EMB_D; ++k) s += wrow[IN_DIM + k] * e_s[k];
    Xemb[(size_t)e * R5 + r] = s;
}

// ---------------------------------------------------------------------------
// Kernel 3 (ONCE): x-part GEMM for all 4096 steps.
//   Hbuf[t][r] = Wx_r . features[proc_order[t]],  r in [0,5120), K=1024
// 128x128 tile, BK=16, 256 threads, 8x8 split micro-tile (all LDS reads <=2-way).
// ---------------------------------------------------------------------------
__global__ __launch_bounds__(256)
void xgemm(const float* __restrict__ features,
           const int* __restrict__ proc_order,
           const float* __restrict__ W_px,
           const float* __restrict__ W_ioux,
           const float* __restrict__ W_fx,
           float* __restrict__ Hbuf)
{
    const int bn = blockIdx.x;   // output-row tile, 0..39
    const int bm = blockIdx.y;   // node tile, 0..31
    const int tid = threadIdx.x;

    __shared__ __align__(16) float As[16][132];
    __shared__ __align__(16) float Bs[16][132];
    __shared__ int s_feat[128];

    if (tid < 128) s_feat[tid] = proc_order[bm * 128 + tid];
    __syncthreads();

    const int arow = tid >> 1;            // 0..127
    const int akc  = (tid & 1) << 3;      // 0 or 8
    const float* afeat = features + (size_t)s_feat[arow] * IN_DIM;

    const int r_base = bn * 128;
    const int rg = r_base + arow;
    const float* wrow;
    if (rg < HID)          wrow = W_px   + (size_t)rg * IN_SZ;
    else if (rg < 4 * HID) wrow = W_ioux + (size_t)(rg - HID) * IN_SZ;
    else                   wrow = W_fx   + (size_t)(rg - 4 * HID) * IN_SZ;

    const int tx = tid & 15, ty = tid >> 4;

    float acc[8][8];
    #pragma unroll
    for (int i = 0; i < 8; ++i)
        #pragma unroll
        for (int j = 0; j < 8; ++j) acc[i][j] = 0.f;

    for (int kt = 0; kt < IN_DIM; kt += 16) {
        float4 a0 = *(const float4*)(afeat + kt + akc);
        float4 a1 = *(const float4*)(afeat + kt + akc + 4);
        float4 b0 = *(const float4*)(wrow + kt + akc);
        float4 b1 = *(const float4*)(wrow + kt + akc + 4);
        __syncthreads();   // previous iter's LDS reads done
        As[akc + 0][arow] = a0.x; As[akc + 1][arow] = a0.y; As[akc + 2][arow] = a0.z; As[akc + 3][arow] = a0.w;
        As[akc + 4][arow] = a1.x; As[akc + 5][arow] = a1.y; As[akc + 6][arow] = a1.z; As[akc + 7][arow] = a1.w;
        Bs[akc + 0][arow] = b0.x; Bs[akc + 1][arow] = b0.y; Bs[akc + 2][arow] = b0.z; Bs[akc + 3][arow] = b0.w;
        Bs[akc + 4][arow] = b1.x; Bs[akc + 5][arow] = b1.y; Bs[akc + 6][arow] = b1.z; Bs[akc + 7][arow] = b1.w;
        __syncthreads();
        #pragma unroll
        for (int k = 0; k < 16; ++k) {
            float4 A0 = *(const float4*)&As[k][ty * 4];
            float4 A1 = *(const float4*)&As[k][64 + ty * 4];
            float4 B0 = *(const float4*)&Bs[k][tx * 4];
            float4 B1 = *(const float4*)&Bs[k][64 + tx * 4];
            float av[8] = {A0.x, A0.y, A0.z, A0.w, A1.x, A1.y, A1.z, A1.w};
            float bv[8] = {B0.x, B0.y, B0.z, B0.w, B1.x, B1.y, B1.z, B1.w};
            #pragma unroll
            for (int i = 0; i < 8; ++i)
                #pragma unroll
                for (int j = 0; j < 8; ++j)
                    acc[i][j] = fmaf(av[i], bv[j], acc[i][j]);
        }
    }

    const int t0 = bm * 128;
    #pragma unroll
    for (int i = 0; i < 8; ++i) {
        int mr = (i < 4) ? (ty * 4 + i) : (64 + ty * 4 + (i - 4));
        float* dst = Hbuf + (size_t)(t0 + mr) * R5 + r_base;
        *(float4*)(dst + tx * 4)      = make_float4(acc[i][0], acc[i][1], acc[i][2], acc[i][3]);
        *(float4*)(dst + 64 + tx * 4) = make_float4(acc[i][4], acc[i][5], acc[i][6], acc[i][7]);
    }
}

// ---------------------------------------------------------------------------
// Kernel 4 (per level, l>=1): h-part GEMM, accumulate into Hbuf rows [1024,5120).
//   Hbuf[t][1024+r] += Wh_r . h_all[parent(t)],  r in [0,4096), K=1024
// 64(nodes) x 128(rows) tile, BK=16, 128 threads, 8x8 split micro-tile.
// ---------------------------------------------------------------------------
__global__ __launch_bounds__(128)
void hgemm(int lvl,
           const int* __restrict__ level_start,
           const int* __restrict__ level_nodes,
           const int* __restrict__ parent_pos,
           const float* __restrict__ h_all,
           const float* __restrict__ W_iouh,
           const float* __restrict__ W_fh,
           float* __restrict__ Hbuf)
{
    const int s0 = level_start[lvl];
    const int n  = level_start[lvl + 1] - s0;
    const int bm = blockIdx.y;
    if (bm * 64 >= n) return;           // uniform exit before any barrier
    const int bn = blockIdx.x;          // 0..31
    const int tid = threadIdx.x;

    __shared__ __align__(16) float As[16][68];
    __shared__ __align__(16) float Bs[16][132];
    __shared__ int s_node[64];
    __shared__ int s_par[64];

    if (tid < 64) {
        int m = bm * 64 + tid;
        if (m < n) {
            int t = level_nodes[s0 + m];
            s_node[tid] = t;
            s_par[tid]  = parent_pos[t];
        } else { s_node[tid] = -1; s_par[tid] = -1; }
    }
    __syncthreads();

    const int arow = tid >> 1;            // 0..63
    const int akc  = (tid & 1) << 3;      // 0 or 8
    const int p = s_par[arow];
    const float* ah = (p >= 0) ? (h_all + (size_t)p * HID) : nullptr;

    const int rg = bn * 128 + tid;        // 0..4095
    const float* wrow = (rg < 3 * HID) ? (W_iouh + (size_t)rg * HID)
                                       : (W_fh + (size_t)(rg - 3 * HID) * HID);

    const int tx = tid & 15, ty = tid >> 4;   // ty 0..7

    float acc[8][8];
    #pragma unroll
    for (int i = 0; i < 8; ++i)
        #pragma unroll
        for (int j = 0; j < 8; ++j) acc[i][j] = 0.f;

    for (int kt = 0; kt < HID; kt += 16) {
        float4 a0, a1;
        if (ah) {
            a0 = *(const float4*)(ah + kt + akc);
            a1 = *(const float4*)(ah + kt + akc + 4);
        } else {
            a0 = make_float4(0.f, 0.f, 0.f, 0.f); a1 = a0;
        }
        float4 b0 = *(const float4*)(wrow + kt);
        float4 b1 = *(const float4*)(wrow + kt + 4);
        float4 b2 = *(const float4*)(wrow + kt + 8);
        float4 b3 = *(const float4*)(wrow + kt + 12);
        __syncthreads();
        As[akc + 0][arow] = a0.x; As[akc + 1][arow] = a0.y; As[akc + 2][arow] = a0.z; As[akc + 3][arow] = a0.w;
        As[akc + 4][arow] = a1.x; As[akc + 5][arow] = a1.y; As[akc + 6][arow] = a1.z; As[akc + 7][arow] = a1.w;
        Bs[0][tid] = b0.x;  Bs[1][tid] = b0.y;  Bs[2][tid] = b0.z;  Bs[3][tid] = b0.w;
        Bs[4][tid] = b1.x;  Bs[5][tid] = b1.y;  Bs[6][tid] = b1.z;  Bs[7][tid] = b1.w;
        Bs[8][tid] = b2.x;  Bs[9][tid] = b2.y;  Bs[10][tid] = b2.z; Bs[11][tid] = b2.w;
        Bs[12][tid] = b3.x; Bs[13][tid] = b3.y; Bs[14][tid] = b3.z; Bs[15][tid] = b3.w;
        __syncthreads();
        #pragma unroll
        for (int k = 0; k < 16; ++k) {
            float4 A0 = *(const float4*)&As[k][ty * 4];
            float4 A1 = *(const float4*)&As[k][32 + ty * 4];
            float4 B0 = *(const float4*)&Bs[k][tx * 4];
            float4 B1 = *(const float4*)&Bs[k][64 + tx * 4];
            float av[8] = {A0.x, A0.y, A0.z, A0.w, A1.x, A1.y, A1.z, A1.w};
            float bv[8] = {B0.x, B0.y, B0.z, B0.w, B1.x, B1.y, B1.z, B1.w};
            #pragma unroll
            for (int i = 0; i < 8; ++i)
                #pragma unroll
                for (int j = 0; j < 8; ++j)
                    acc[i][j] = fmaf(av[i], bv[j], acc[i][j]);
        }
    }

    #pragma unroll
    for (int i = 0; i < 8; ++i) {
        int mr = (i < 4) ? (ty * 4 + i) : (32 + ty * 4 + (i - 4));
        if (bm * 64 + mr < n) {
            int t = s_node[mr];
            float* dst = Hbuf + (size_t)t * R5 + HID + bn * 128;
            float4 o0 = *(const float4*)(dst + tx * 4);
            float4 o1 = *(const float4*)(dst + 64 + tx * 4);
            o0.x += acc[i][0]; o0.y += acc[i][1]; o0.z += acc[i][2]; o0.w += acc[i][3];
            o1.x += acc[i][4]; o1.y += acc[i][5]; o1.z += acc[i][6]; o1.w += acc[i][7];
            *(float4*)(dst + tx * 4)      = o0;
            *(float4*)(dst + 64 + tx * 4) = o1;
        }
    }
}

// ---------------------------------------------------------------------------
// Kernel 5 (per level): gates + cell update + output dist + argmax.
// ---------------------------------------------------------------------------
__global__ __launch_bounds__(256)
void level_gates(int lvl,
                 const int* __restrict__ level_start,
                 const int* __restrict__ level_nodes,
                 const int* __restrict__ proc_order,
                 const int* __restrict__ parent_pos,
                 const float* __restrict__ Hbuf,
                 const float* __restrict__ Xemb,
                 const float* __restrict__ b_px,
                 const float* __restrict__ b_ioux,
                 const float* __restrict__ b_iouh,
                 const float* __restrict__ b_fx,
                 const float* __restrict__ b_fh,
                 const float* __restrict__ W_out,
                 const float* __restrict__ b_out,
                 float* __restrict__ h_all,
                 float* __restrict__ c_all,
                 int* __restrict__ eidx_all,
                 float* __restrict__ out)
{
    const int s0 = level_start[lvl];
    const int n  = level_start[lvl + 1] - s0;
    const int tid = threadIdx.x;

    __shared__ __align__(16) float hs[HID];
    __shared__ float bv_s[4];
    __shared__ int   bi_s[4];

    const float4* Bpx4 = (const float4*)b_px;
    const float4* Bxi4 = (const float4*)b_ioux;
    const float4* Bhi4 = (const float4*)b_iouh;
    const float4* Bfx4 = (const float4*)b_fx;
    const float4* Bfh4 = (const float4*)b_fh;

    for (int slot = blockIdx.x; slot < n; slot += gridDim.x) {
        const int t = level_nodes[s0 + slot];
        const int pid = parent_pos[t];
        const int eidx = (pid < 0) ? 0 : eidx_all[pid];

        const float4* H4 = (const float4*)(Hbuf + (size_t)t * R5);
        const float4* E4 = (const float4*)(Xemb + (size_t)eidx * R5);

        float4 Hpx = H4[tid],        Epx = E4[tid];
        float4 Hi  = H4[256 + tid],  Ei  = E4[256 + tid];
        float4 Ho  = H4[512 + tid],  Eo  = E4[512 + tid];
        float4 Hu  = H4[768 + tid],  Eu  = E4[768 + tid];
        float4 Hf  = H4[1024 + tid], Ef  = E4[1024 + tid];
        float4 Bpx = Bpx4[tid];
        float4 Bxi = Bxi4[tid], Bxo = Bxi4[256 + tid], Bxu = Bxi4[512 + tid];
        float4 Bhi = Bhi4[tid], Bho = Bhi4[256 + tid], Bhu = Bhi4[512 + tid];
        float4 Bfx = Bfx4[tid], Bfh = Bfh4[tid];
        float4 PC = (pid < 0) ? make_float4(0.f, 0.f, 0.f, 0.f)
                              : ((const float4*)(c_all + (size_t)pid * HID))[tid];

        float cv[4], hv[4];
#define GATE(CP, IDX) { \
        float pxv = Hpx.CP + Epx.CP + Bpx.CP; \
        float iv  = Hi.CP + Ei.CP + Bxi.CP + Bhi.CP; \
        float ov  = Ho.CP + Eo.CP + Bxo.CP + Bho.CP; \
        float uv  = Hu.CP + Eu.CP + Bxu.CP + Bhu.CP; \
        float fv  = Hf.CP + Ef.CP + Bfx.CP + Bfh.CP; \
        float ig = sigf(iv), og = sigf(ov), ug = tanhf(uv), fg = sigf(fv); \
        float cc = ig * ug + fg * PC.CP; \
        cv[IDX] = cc; \
        hv[IDX] = og * tanhf(cc) * sigf(pxv); }
        GATE(x, 0) GATE(y, 1) GATE(z, 2) GATE(w, 3)
#undef GATE

        float4 c4 = make_float4(cv[0], cv[1], cv[2], cv[3]);
        float4 h4 = make_float4(hv[0], hv[1], hv[2], hv[3]);
        ((float4*)(c_all + (size_t)t * HID))[tid] = c4;
        ((float4*)(h_all + (size_t)t * HID))[tid] = h4;
        ((float4*)hs)[tid] = h4;
        __syncthreads();

        const int node = proc_order[t];
        float* dists = out + (size_t)node * NCLS;
        const int wave = tid >> 6, lane = tid & 63;

        float bv = -3.4e38f; int bi = NCLS;
        for (int r = wave; r < NCLS; r += 4) {
            const float* wr = W_out + (size_t)r * HID;
            float s = 0.f;
            #pragma unroll
            for (int q = 0; q < 4; ++q) {
                float4 w4 = *(const float4*)(wr + (lane << 2) + q * 256);
                float4 x4 = *(const float4*)(hs + (lane << 2) + q * 256);
                s += w4.x * x4.x + w4.y * x4.y + w4.z * x4.z + w4.w * x4.w;
            }
            #pragma unroll
            for (int off = 32; off > 0; off >>= 1) s += __shfl_down(s, off, 64);
            if (lane == 0) {
                s += b_out[r];
                dists[r] = s;
                if (r >= 1 && s > bv) { bv = s; bi = r; }
            }
        }
        if (lane == 0) { bv_s[wave] = bv; bi_s[wave] = bi; }
        __syncthreads();
        if (tid == 0) {
            float v = bv_s[0]; int b = bi_s[0];
            for (int w = 1; w < 4; ++w) {
                if (bv_s[w] > v || (bv_s[w] == v && bi_s[w] < b)) { v = bv_s[w]; b = bi_s[w]; }
            }
            eidx_all[t] = b + 1;
            out[(size_t)N_OBJ * NCLS + node] = (float)b;
        }
        __syncthreads();   // hs / bv_s reused next slot
    }
}

// ---------------------------------------------------------------------------
extern "C" void kernel_launch(void* const* d_in, const int* in_sizes, int n_in,
                              void* d_out, int out_size, void* d_ws, size_t ws_size,
                              hipStream_t stream)
{
    const float* features = (const float*)d_in[0];
    const float* embed_W  = (const float*)d_in[1];
    const float* W_px     = (const float*)d_in[2];
    const float* b_px     = (const float*)d_in[3];
    const float* W_ioux   = (const float*)d_in[4];
    const float* b_ioux   = (const float*)d_in[5];
    const float* W_iouh   = (const float*)d_in[6];
    const float* b_iouh   = (const float*)d_in[7];
    const float* W_fx     = (const float*)d_in[8];
    const float* b_fx     = (const float*)d_in[9];
    const float* W_fh     = (const float*)d_in[10];
    const float* b_fh     = (const float*)d_in[11];
    const float* W_out    = (const float*)d_in[12];
    const float* b_out    = (const float*)d_in[13];
    const int* proc_order = (const int*)d_in[14];
    const int* parent_pos = (const int*)d_in[15];
    float* out = (float*)d_out;

    // workspace layout (~121 MB)
    float* Hbuf  = (float*)d_ws;                      // [N_OBJ][R5]
    float* h_all = Hbuf + (size_t)N_OBJ * R5;         // [N_OBJ][HID]
    float* c_all = h_all + (size_t)N_OBJ * HID;       // [N_OBJ][HID]
    float* Xemb  = c_all + (size_t)N_OBJ * HID;       // [NEMB][R5]
    int* eidx_all    = (int*)(Xemb + (size_t)NEMB * R5);
    int* level_nodes = eidx_all + N_OBJ;
    int* level_start = level_nodes + N_OBJ;

    build_levels<<<1, 1024, 0, stream>>>(parent_pos, level_nodes, level_start);
    xemb_kernel<<<dim3(NEMB, R5 / 256), 256, 0, stream>>>(embed_W, W_px, W_ioux, W_fx, Xemb);
    xgemm<<<dim3(R5 / 128, N_OBJ / 128), 256, 0, stream>>>(
        features, proc_order, W_px, W_ioux, W_fx, Hbuf);

    level_gates<<<1024, 256, 0, stream>>>(
        0, level_start, level_nodes, proc_order, parent_pos,
        Hbuf, Xemb, b_px, b_ioux, b_iouh, b_fx, b_fh, W_out, b_out,
        h_all, c_all, eidx_all, out);

    for (int l = 1; l < MAXLVL; ++l) {
        hgemm<<<dim3(RH / 128, N_OBJ / 64), 128, 0, stream>>>(
            l, level_start, level_nodes, parent_pos, h_all, W_iouh, W_fh, Hbuf);
        level_gates<<<1024, 256, 0, stream>>>(
            l, level_start, level_nodes, proc_order, parent_pos,
            Hbuf, Xemb, b_px, b_ioux, b_iouh, b_fx, b_fh, W_out, b_out,
            h_all, c_all, eidx_all, out);
    }
}

// Round 3
// 2101.002 us; speedup vs baseline: 1.6353x; 1.6063x over previous
//
#include <hip/hip_runtime.h>
#include <hip/hip_bf16.h>
#include <math.h>

#define N_OBJ 4096
#define IN_DIM 1024
#define EMB_D 200
#define HID 1024
#define NCLS 151
#define IN_SZ 1224      // IN_DIM + EMB_D
#define NEMB 152        // NCLS + 1 embedding rows
#define R5 5120         // px(1024) + iou(3072) + f(1024) pre-activation rows
#define RH 4096         // h-dependent rows (iou 3072 + f 1024)
#define MAXLVL 40

__device__ __forceinline__ float sigf(float x) { return 1.f / (1.f + expf(-x)); }

// ---------------------------------------------------------------------------
// Kernel 1: depth per step, bucket steps by level (single block).
// ---------------------------------------------------------------------------
__global__ __launch_bounds__(1024)
void build_levels(const int* __restrict__ parent_pos,
                  int* __restrict__ level_nodes,
                  int* __restrict__ level_start)
{
    __shared__ int dep[N_OBJ];
    __shared__ int par[N_OBJ];
    __shared__ int cnt[MAXLVL];
    __shared__ int offs[MAXLVL];
    __shared__ int base[MAXLVL + 1];
    __shared__ int done;
    const int tid = threadIdx.x;

    for (int t = tid; t < N_OBJ; t += 1024) {
        int p = parent_pos[t];
        par[t] = p;
        dep[t] = (p < 0) ? 0 : -1;
    }
    for (int l = tid; l < MAXLVL; l += 1024) { cnt[l] = 0; offs[l] = 0; }
    __syncthreads();

    for (int it = 0; it < 64; ++it) {
        if (tid == 0) done = 1;
        __syncthreads();
        for (int t = tid; t < N_OBJ; t += 1024) {
            if (dep[t] < 0) {
                int dp = dep[par[t]];
                if (dp >= 0) dep[t] = dp + 1;
                else done = 0;
            }
        }
        __syncthreads();
        int d = done;
        __syncthreads();
        if (d) break;
    }

    for (int t = tid; t < N_OBJ; t += 1024) {
        int d = dep[t];
        if (d < 0 || d >= MAXLVL) d = MAXLVL - 1;  // safety clamp
        dep[t] = d;
        atomicAdd(&cnt[d], 1);
    }
    __syncthreads();
    if (tid == 0) {
        base[0] = 0;
        for (int l = 0; l < MAXLVL; ++l) base[l + 1] = base[l] + cnt[l];
    }
    __syncthreads();
    for (int t = tid; t < N_OBJ; t += 1024) {
        int d = dep[t];
        int pos = base[d] + atomicAdd(&offs[d], 1);
        level_nodes[pos] = t;
    }
    for (int l = tid; l <= MAXLVL; l += 1024) level_start[l] = base[l];
}

// ---------------------------------------------------------------------------
// Kernel 2: Xemb[e][r] = W_row_r[:, 1024:1224] @ embed_W[e] + (all biases)
// ---------------------------------------------------------------------------
__global__ __launch_bounds__(256)
void xemb_kernel(const float* __restrict__ embed_W,
                 const float* __restrict__ W_px,
                 const float* __restrict__ W_ioux,
                 const float* __restrict__ W_fx,
                 const float* __restrict__ b_px,
                 const float* __restrict__ b_ioux,
                 const float* __restrict__ b_iouh,
                 const float* __restrict__ b_fx,
                 const float* __restrict__ b_fh,
                 float* __restrict__ Xemb)
{
    __shared__ float e_s[EMB_D];
    const int e = blockIdx.x;
    const int r = blockIdx.y * 256 + threadIdx.x;
    for (int k = threadIdx.x; k < EMB_D; k += 256) e_s[k] = embed_W[(size_t)e * EMB_D + k];
    __syncthreads();

    const float* wrow;
    float bias;
    if (r < HID) {
        wrow = W_px + (size_t)r * IN_SZ;
        bias = b_px[r];
    } else if (r < 4 * HID) {
        wrow = W_ioux + (size_t)(r - HID) * IN_SZ;
        bias = b_ioux[r - HID] + b_iouh[r - HID];
    } else {
        wrow = W_fx + (size_t)(r - 4 * HID) * IN_SZ;
        bias = b_fx[r - 4 * HID] + b_fh[r - 4 * HID];
    }

    float s = bias;
    for (int k = 0; k < EMB_D; ++k) s += wrow[IN_DIM + k] * e_s[k];
    Xemb[(size_t)e * R5 + r] = s;
}

// ---------------------------------------------------------------------------
// Kernel 3 (ONCE): x-part GEMM, Hbuf[t][r] = Wx_r . features[proc_order[t]]
// 128x128 tile, BK=16, 256 threads, 8x8 split micro-tile, reg prefetch.
// ---------------------------------------------------------------------------
__global__ __launch_bounds__(256)
void xgemm(const float* __restrict__ features,
           const int* __restrict__ proc_order,
           const float* __restrict__ W_px,
           const float* __restrict__ W_ioux,
           const float* __restrict__ W_fx,
           float* __restrict__ Hbuf)
{
    const int bn = blockIdx.x;   // output-row tile, 0..39
    const int bm = blockIdx.y;   // node tile, 0..31
    const int tid = threadIdx.x;

    __shared__ __align__(16) float As[16][132];
    __shared__ __align__(16) float Bs[16][132];
    __shared__ int s_feat[128];

    if (tid < 128) s_feat[tid] = proc_order[bm * 128 + tid];
    __syncthreads();

    const int arow = tid >> 1;            // 0..127
    const int akc  = (tid & 1) << 3;      // 0 or 8
    const float* afeat = features + (size_t)s_feat[arow] * IN_DIM;

    const int r_base = bn * 128;
    const int rg = r_base + arow;
    const float* wrow;
    if (rg < HID)          wrow = W_px   + (size_t)rg * IN_SZ;
    else if (rg < 4 * HID) wrow = W_ioux + (size_t)(rg - HID) * IN_SZ;
    else                   wrow = W_fx   + (size_t)(rg - 4 * HID) * IN_SZ;

    const int tx = tid & 15, ty = tid >> 4;

    float acc[8][8];
    #pragma unroll
    for (int i = 0; i < 8; ++i)
        #pragma unroll
        for (int j = 0; j < 8; ++j) acc[i][j] = 0.f;

    float4 a0 = *(const float4*)(afeat + akc);
    float4 a1 = *(const float4*)(afeat + akc + 4);
    float4 b0 = *(const float4*)(wrow + akc);
    float4 b1 = *(const float4*)(wrow + akc + 4);

    for (int kt = 0; kt < IN_DIM; kt += 16) {
        __syncthreads();   // previous iter's LDS reads done
        As[akc + 0][arow] = a0.x; As[akc + 1][arow] = a0.y; As[akc + 2][arow] = a0.z; As[akc + 3][arow] = a0.w;
        As[akc + 4][arow] = a1.x; As[akc + 5][arow] = a1.y; As[akc + 6][arow] = a1.z; As[akc + 7][arow] = a1.w;
        Bs[akc + 0][arow] = b0.x; Bs[akc + 1][arow] = b0.y; Bs[akc + 2][arow] = b0.z; Bs[akc + 3][arow] = b0.w;
        Bs[akc + 4][arow] = b1.x; Bs[akc + 5][arow] = b1.y; Bs[akc + 6][arow] = b1.z; Bs[akc + 7][arow] = b1.w;
        __syncthreads();
        if (kt + 16 < IN_DIM) {   // prefetch next tile while computing this one
            a0 = *(const float4*)(afeat + kt + 16 + akc);
            a1 = *(const float4*)(afeat + kt + 16 + akc + 4);
            b0 = *(const float4*)(wrow + kt + 16 + akc);
            b1 = *(const float4*)(wrow + kt + 16 + akc + 4);
        }
        #pragma unroll
        for (int k = 0; k < 16; ++k) {
            float4 A0 = *(const float4*)&As[k][ty * 4];
            float4 A1 = *(const float4*)&As[k][64 + ty * 4];
            float4 B0 = *(const float4*)&Bs[k][tx * 4];
            float4 B1 = *(const float4*)&Bs[k][64 + tx * 4];
            float av[8] = {A0.x, A0.y, A0.z, A0.w, A1.x, A1.y, A1.z, A1.w};
            float bv[8] = {B0.x, B0.y, B0.z, B0.w, B1.x, B1.y, B1.z, B1.w};
            #pragma unroll
            for (int i = 0; i < 8; ++i)
                #pragma unroll
                for (int j = 0; j < 8; ++j)
                    acc[i][j] = fmaf(av[i], bv[j], acc[i][j]);
        }
    }

    const int t0 = bm * 128;
    #pragma unroll
    for (int i = 0; i < 8; ++i) {
        int mr = (i < 4) ? (ty * 4 + i) : (64 + ty * 4 + (i - 4));
        float* dst = Hbuf + (size_t)(t0 + mr) * R5 + r_base;
        *(float4*)(dst + tx * 4)      = make_float4(acc[i][0], acc[i][1], acc[i][2], acc[i][3]);
        *(float4*)(dst + 64 + tx * 4) = make_float4(acc[i][4], acc[i][5], acc[i][6], acc[i][7]);
    }
}

// ---------------------------------------------------------------------------
// Kernel 4 (per level, l>=1): Hbuf[t][1024+r] += Wh_r . h_all[parent(t)]
// 64(nodes) x 64(rows) tile, BK=32, 256 threads, 4x4 micro-tile, reg prefetch.
// Per-thread serial work = 16384 FMA (4x less than round-2 version).
// ---------------------------------------------------------------------------
__global__ __launch_bounds__(256)
void hgemm(int lvl,
           const int* __restrict__ level_start,
           const int* __restrict__ level_nodes,
           const int* __restrict__ parent_pos,
           const float* __restrict__ h_all,
           const float* __restrict__ W_iouh,
           const float* __restrict__ W_fh,
           float* __restrict__ Hbuf)
{
    const int s0 = level_start[lvl];
    const int n  = level_start[lvl + 1] - s0;
    const int bm = blockIdx.y;
    if (bm * 64 >= n) return;           // uniform exit before any barrier
    const int bn = blockIdx.x;          // 0..63 row-blocks
    const int tid = threadIdx.x;

    __shared__ __align__(16) float As[32][68];
    __shared__ __align__(16) float Bs[32][68];
    __shared__ int s_node[64];
    __shared__ int s_par[64];

    if (tid < 64) {
        int m = bm * 64 + tid;
        if (m < n) {
            int t = level_nodes[s0 + m];
            s_node[tid] = t;
            s_par[tid]  = parent_pos[t];
        } else { s_node[tid] = -1; s_par[tid] = -1; }
    }
    __syncthreads();

    const int arow = tid >> 2;            // 0..63
    const int akc  = (tid & 3) << 3;      // 0,8,16,24
    const int p = s_par[arow];
    const float* ah = (p >= 0) ? (h_all + (size_t)p * HID) : nullptr;

    const int rg = bn * 64 + arow;        // 0..4095
    const float* wrow = (rg < 3 * HID) ? (W_iouh + (size_t)rg * HID)
                                       : (W_fh + (size_t)(rg - 3 * HID) * HID);

    const int tx = tid & 15, ty = tid >> 4;   // tx: row quad, ty: node quad

    float acc[4][4];
    #pragma unroll
    for (int i = 0; i < 4; ++i)
        #pragma unroll
        for (int j = 0; j < 4; ++j) acc[i][j] = 0.f;

    float4 a0, a1;
    if (ah) { a0 = *(const float4*)(ah + akc); a1 = *(const float4*)(ah + akc + 4); }
    else    { a0 = make_float4(0.f, 0.f, 0.f, 0.f); a1 = a0; }
    float4 b0 = *(const float4*)(wrow + akc);
    float4 b1 = *(const float4*)(wrow + akc + 4);

    for (int kt = 0; kt < HID; kt += 32) {
        __syncthreads();
        As[akc + 0][arow] = a0.x; As[akc + 1][arow] = a0.y; As[akc + 2][arow] = a0.z; As[akc + 3][arow] = a0.w;
        As[akc + 4][arow] = a1.x; As[akc + 5][arow] = a1.y; As[akc + 6][arow] = a1.z; As[akc + 7][arow] = a1.w;
        Bs[akc + 0][arow] = b0.x; Bs[akc + 1][arow] = b0.y; Bs[akc + 2][arow] = b0.z; Bs[akc + 3][arow] = b0.w;
        Bs[akc + 4][arow] = b1.x; Bs[akc + 5][arow] = b1.y; Bs[akc + 6][arow] = b1.z; Bs[akc + 7][arow] = b1.w;
        __syncthreads();
        if (kt + 32 < HID) {   // prefetch next k-tile
            if (ah) {
                a0 = *(const float4*)(ah + kt + 32 + akc);
                a1 = *(const float4*)(ah + kt + 32 + akc + 4);
            }
            b0 = *(const float4*)(wrow + kt + 32 + akc);
            b1 = *(const float4*)(wrow + kt + 32 + akc + 4);
        }
        #pragma unroll
        for (int k = 0; k < 32; ++k) {
            float4 A = *(const float4*)&As[k][ty * 4];   // 4 distinct addrs -> broadcast
            float4 B = *(const float4*)&Bs[k][tx * 4];   // 64 consecutive -> 2-way (free)
            acc[0][0] = fmaf(A.x, B.x, acc[0][0]); acc[0][1] = fmaf(A.x, B.y, acc[0][1]);
            acc[0][2] = fmaf(A.x, B.z, acc[0][2]); acc[0][3] = fmaf(A.x, B.w, acc[0][3]);
            acc[1][0] = fmaf(A.y, B.x, acc[1][0]); acc[1][1] = fmaf(A.y, B.y, acc[1][1]);
            acc[1][2] = fmaf(A.y, B.z, acc[1][2]); acc[1][3] = fmaf(A.y, B.w, acc[1][3]);
            acc[2][0] = fmaf(A.z, B.x, acc[2][0]); acc[2][1] = fmaf(A.z, B.y, acc[2][1]);
            acc[2][2] = fmaf(A.z, B.z, acc[2][2]); acc[2][3] = fmaf(A.z, B.w, acc[2][3]);
            acc[3][0] = fmaf(A.w, B.x, acc[3][0]); acc[3][1] = fmaf(A.w, B.y, acc[3][1]);
            acc[3][2] = fmaf(A.w, B.z, acc[3][2]); acc[3][3] = fmaf(A.w, B.w, acc[3][3]);
        }
    }

    #pragma unroll
    for (int i = 0; i < 4; ++i) {
        int ml = ty * 4 + i;
        if (bm * 64 + ml < n) {
            int t = s_node[ml];
            float* dst = Hbuf + (size_t)t * R5 + HID + bn * 64 + tx * 4;
            float4 o = *(const float4*)dst;
            o.x += acc[i][0]; o.y += acc[i][1]; o.z += acc[i][2]; o.w += acc[i][3];
            *(float4*)dst = o;
        }
    }
}

// ---------------------------------------------------------------------------
// Kernel 5 (per level): gates + cell update + output dist + argmax.
// Biases are pre-folded into Xemb.
// ---------------------------------------------------------------------------
__global__ __launch_bounds__(256)
void level_gates(int lvl,
                 const int* __restrict__ level_start,
                 const int* __restrict__ level_nodes,
                 const int* __restrict__ proc_order,
                 const int* __restrict__ parent_pos,
                 const float* __restrict__ Hbuf,
                 const float* __restrict__ Xemb,
                 const float* __restrict__ W_out,
                 const float* __restrict__ b_out,
                 float* __restrict__ h_all,
                 float* __restrict__ c_all,
                 int* __restrict__ eidx_all,
                 float* __restrict__ out)
{
    const int s0 = level_start[lvl];
    const int n  = level_start[lvl + 1] - s0;
    const int tid = threadIdx.x;

    __shared__ __align__(16) float hs[HID];
    __shared__ float bv_s[4];
    __shared__ int   bi_s[4];

    for (int slot = blockIdx.x; slot < n; slot += gridDim.x) {
        const int t = level_nodes[s0 + slot];
        const int pid = parent_pos[t];
        const int eidx = (pid < 0) ? 0 : eidx_all[pid];

        const float4* H4 = (const float4*)(Hbuf + (size_t)t * R5);
        const float4* E4 = (const float4*)(Xemb + (size_t)eidx * R5);

        float4 Hpx = H4[tid],        Epx = E4[tid];
        float4 Hi  = H4[256 + tid],  Ei  = E4[256 + tid];
        float4 Ho  = H4[512 + tid],  Eo  = E4[512 + tid];
        float4 Hu  = H4[768 + tid],  Eu  = E4[768 + tid];
        float4 Hf  = H4[1024 + tid], Ef  = E4[1024 + tid];
        float4 PC = (pid < 0) ? make_float4(0.f, 0.f, 0.f, 0.f)
                              : ((const float4*)(c_all + (size_t)pid * HID))[tid];

        float cv[4], hv[4];
#define GATE(CP, IDX) { \
        float pxv = Hpx.CP + Epx.CP; \
        float iv  = Hi.CP + Ei.CP; \
        float ov  = Ho.CP + Eo.CP; \
        float uv  = Hu.CP + Eu.CP; \
        float fv  = Hf.CP + Ef.CP; \
        float ig = sigf(iv), og = sigf(ov), ug = tanhf(uv), fg = sigf(fv); \
        float cc = ig * ug + fg * PC.CP; \
        cv[IDX] = cc; \
        hv[IDX] = og * tanhf(cc) * sigf(pxv); }
        GATE(x, 0) GATE(y, 1) GATE(z, 2) GATE(w, 3)
#undef GATE

        float4 c4 = make_float4(cv[0], cv[1], cv[2], cv[3]);
        float4 h4 = make_float4(hv[0], hv[1], hv[2], hv[3]);
        ((float4*)(c_all + (size_t)t * HID))[tid] = c4;
        ((float4*)(h_all + (size_t)t * HID))[tid] = h4;
        ((float4*)hs)[tid] = h4;
        __syncthreads();

        const int node = proc_order[t];
        float* dists = out + (size_t)node * NCLS;
        const int wave = tid >> 6, lane = tid & 63;

        float bv = -3.4e38f; int bi = NCLS;
        for (int r = wave; r < NCLS; r += 4) {
            const float* wr = W_out + (size_t)r * HID;
            float s = 0.f;
            #pragma unroll
            for (int q = 0; q < 4; ++q) {
                float4 w4 = *(const float4*)(wr + (lane << 2) + q * 256);
                float4 x4 = *(const float4*)(hs + (lane << 2) + q * 256);
                s += w4.x * x4.x + w4.y * x4.y + w4.z * x4.z + w4.w * x4.w;
            }
            #pragma unroll
            for (int off = 32; off > 0; off >>= 1) s += __shfl_down(s, off, 64);
            if (lane == 0) {
                s += b_out[r];
                dists[r] = s;
                if (r >= 1 && s > bv) { bv = s; bi = r; }
            }
        }
        if (lane == 0) { bv_s[wave] = bv; bi_s[wave] = bi; }
        __syncthreads();
        if (tid == 0) {
            float v = bv_s[0]; int b = bi_s[0];
            for (int w = 1; w < 4; ++w) {
                if (bv_s[w] > v || (bv_s[w] == v && bi_s[w] < b)) { v = bv_s[w]; b = bi_s[w]; }
            }
            eidx_all[t] = b + 1;
            out[(size_t)N_OBJ * NCLS + node] = (float)b;
        }
        __syncthreads();   // hs / bv_s reused next slot
    }
}

// ---------------------------------------------------------------------------
extern "C" void kernel_launch(void* const* d_in, const int* in_sizes, int n_in,
                              void* d_out, int out_size, void* d_ws, size_t ws_size,
                              hipStream_t stream)
{
    const float* features = (const float*)d_in[0];
    const float* embed_W  = (const float*)d_in[1];
    const float* W_px     = (const float*)d_in[2];
    const float* b_px     = (const float*)d_in[3];
    const float* W_ioux   = (const float*)d_in[4];
    const float* b_ioux   = (const float*)d_in[5];
    const float* W_iouh   = (const float*)d_in[6];
    const float* b_iouh   = (const float*)d_in[7];
    const float* W_fx     = (const float*)d_in[8];
    const float* b_fx     = (const float*)d_in[9];
    const float* W_fh     = (const float*)d_in[10];
    const float* b_fh     = (const float*)d_in[11];
    const float* W_out    = (const float*)d_in[12];
    const float* b_out    = (const float*)d_in[13];
    const int* proc_order = (const int*)d_in[14];
    const int* parent_pos = (const int*)d_in[15];
    float* out = (float*)d_out;

    // workspace layout (~121 MB)
    float* Hbuf  = (float*)d_ws;                      // [N_OBJ][R5]
    float* h_all = Hbuf + (size_t)N_OBJ * R5;         // [N_OBJ][HID]
    float* c_all = h_all + (size_t)N_OBJ * HID;       // [N_OBJ][HID]
    float* Xemb  = c_all + (size_t)N_OBJ * HID;       // [NEMB][R5]
    int* eidx_all    = (int*)(Xemb + (size_t)NEMB * R5);
    int* level_nodes = eidx_all + N_OBJ;
    int* level_start = level_nodes + N_OBJ;

    build_levels<<<1, 1024, 0, stream>>>(parent_pos, level_nodes, level_start);
    xemb_kernel<<<dim3(NEMB, R5 / 256), 256, 0, stream>>>(
        embed_W, W_px, W_ioux, W_fx, b_px, b_ioux, b_iouh, b_fx, b_fh, Xemb);
    xgemm<<<dim3(R5 / 128, N_OBJ / 128), 256, 0, stream>>>(
        features, proc_order, W_px, W_ioux, W_fx, Hbuf);

    level_gates<<<1024, 256, 0, stream>>>(
        0, level_start, level_nodes, proc_order, parent_pos,
        Hbuf, Xemb, W_out, b_out, h_all, c_all, eidx_all, out);

    for (int l = 1; l < MAXLVL; ++l) {
        hgemm<<<dim3(RH / 64, N_OBJ / 64), 256, 0, stream>>>(
            l, level_start, level_nodes, parent_pos, h_all, W_iouh, W_fh, Hbuf);
        level_gates<<<1024, 256, 0, stream>>>(
            l, level_start, level_nodes, proc_order, parent_pos,
            Hbuf, Xemb, W_out, b_out, h_all, c_all, eidx_all, out);
    }
}